// Round 6
// baseline (86.992 us; speedup 1.0000x reference)
//
#include <hip/hip_runtime.h>
#include <hip/hip_bf16.h>
#include <math.h>

#define NPAIR 4096       // N = B*S
#define D 128
#define TWO_N 8192
#define NTILES 8256      // sum_{bi=0}^{127} (128-bi): upper-tri 64x64 tiles
// Rb rows pre-scaled by ALPHA = sqrt(2*log2(e)): MFMA acc == 2*log2(e)*sim,
// so exp(2*sim) == exp2(acc) -> a single raw v_exp_f32 in the epilogue.
#define ALPHA 1.6986436f

typedef float f32x4 __attribute__((ext_vector_type(4)));
typedef int i32x8 __attribute__((ext_vector_type(8)));

__device__ __forceinline__ void async_ld16(void* lds, const void* g) {
    // async global->LDS DMA, 16B/lane; LDS dest = wave-uniform base + lane*16
    __builtin_amdgcn_global_load_lds(
        (__attribute__((address_space(1))) const unsigned int*)g,
        (__attribute__((address_space(3))) unsigned int*)lds, 16, 0, 0);
}

__device__ __forceinline__ i32x8 mk8(uint4 lo, uint4 hi) {
    return (i32x8){(int)lo.x, (int)lo.y, (int)lo.z, (int)lo.w,
                   (int)hi.x, (int)hi.y, (int)hi.z, (int)hi.w};
}

// 512 blocks x 256 threads; half-wave h (32 lanes) handles pair-row
// k = blockIdx*8 + h, 4 elems/lane via float4. Emits ALPHA-scaled fp8 e4m3
// rows, PLAIN ROW-MAJOR, one dword store per lane per row. Zeroes rowsum +
// colpart (8192 floats each) for simexp's atomics (stream-ordered ahead).
// pos[] stays exact fp32. Zero-inits out[0].  [core PASSED r1/r3/r4/r5]
__global__ __launch_bounds__(256) void norm_kernel(const float* __restrict__ zi,
                                                   const float* __restrict__ zj,
                                                   unsigned char* __restrict__ Rb,
                                                   float* __restrict__ pos,
                                                   float* __restrict__ rowsum,
                                                   float* __restrict__ colpart,
                                                   float* __restrict__ out) {
    if (blockIdx.x == 0 && threadIdx.x == 0) out[0] = 0.f;
    if (blockIdx.x < 32)       colpart[blockIdx.x * 256 + threadIdx.x] = 0.f;
    else if (blockIdx.x < 64)  rowsum[(blockIdx.x - 32) * 256 + threadIdx.x] = 0.f;
    int k = blockIdx.x * 8 + (threadIdx.x >> 5);
    int t = threadIdx.x & 31;                 // 4 elems each
    const float4 a = *(const float4*)(zi + k * D + 4 * t);
    const float4 b = *(const float4*)(zj + k * D + 4 * t);
    float si = a.x * a.x + a.y * a.y + a.z * a.z + a.w * a.w;
    float sj = b.x * b.x + b.y * b.y + b.z * b.z + b.w * b.w;
    float dt = a.x * b.x + a.y * b.y + a.z * b.z + a.w * b.w;
    #pragma unroll
    for (int m = 1; m < 32; m <<= 1) {        // reduce within the 32-lane row
        si += __shfl_xor(si, m, 32);
        sj += __shfl_xor(sj, m, 32);
        dt += __shfl_xor(dt, m, 32);
    }
    float ii = 1.0f / fmaxf(sqrtf(si), 1e-12f);
    float ij = 1.0f / fmaxf(sqrtf(sj), 1e-12f);
    if (t == 0) pos[k] = dt * ii * ij;        // exact (unscaled) positive sim
    ii *= ALPHA; ij *= ALPHA;
    int r0 = __builtin_amdgcn_cvt_pk_fp8_f32(a.x * ii, a.y * ii, 0, false);
    r0 = __builtin_amdgcn_cvt_pk_fp8_f32(a.z * ii, a.w * ii, r0, true);
    *(unsigned int*)(Rb + (size_t)k * 128 + 4 * t) = (unsigned int)r0;
    int r1 = __builtin_amdgcn_cvt_pk_fp8_f32(b.x * ij, b.y * ij, 0, false);
    r1 = __builtin_amdgcn_cvt_pk_fp8_f32(b.z * ij, b.w * ij, r1, true);
    *(unsigned int*)(Rb + (size_t)(k + NPAIR) * 128 + 4 * t) = (unsigned int)r1;
}

// BALANCED UPPER-TRIANGLE, r0-proven LDS pipeline. r5 lesson: all 1024
// blocks are co-resident (4/CU) -> duration = per-block time, so slab-level
// masking couldn't pay. Here the 8256 upper-tri 64x64 tiles are split EVENLY
// across 1024 blocks (8-9 tiles each, ~56% of r0's 16). Tile walk:
// (bi, j64), j64 in [bi,128); advance j64++, on overflow bi++, j64=bi.
// Stripe changes flush row partials (atomicAdd into rowsum) + reload the 8
// A-fragment loads (rare). Diag tile (j64==bi): row-sum with diagonal
// zeroed, covers within-tile both triangles. Above tiles (j64>bi): row-sum
// + column sums into colpart (transpose side; each lane's col is fixed ->
// 2 shfl + one 16-lane atomicAdd per tile). Coverage: row r direct = tiles
// >= r>>6, colpart = tiles < r>>6; disjoint, complete.
__global__ __launch_bounds__(256, 4) void simexp_kernel(const unsigned char* __restrict__ Rb,
                                                        float* __restrict__ rowsum,
                                                        float* __restrict__ colpart) {
    const int tid = threadIdx.x;
    const int wave = tid >> 6, lane = tid & 63;
    const int rp = lane & 15, q = lane >> 4;

    // this block's global tile range [g0, g1): 8 or 9 tiles
    const int b = blockIdx.x;
    const int g0 = (NTILES * b) >> 10;
    const int g1 = (NTILES * (b + 1)) >> 10;
    const int nt = g1 - g0;

    // invert C(bi) = bi*(257-bi)/2 <= g0 < C(bi+1)  (float est + exact fixup)
    int bi = (int)((257.0f - sqrtf(66049.0f - 8.0f * (float)g0)) * 0.5f);
    if (bi < 0) bi = 0; if (bi > 127) bi = 127;
    while (bi * (257 - bi) / 2 > g0) --bi;
    while ((bi + 1) * (256 - bi) / 2 <= g0) ++bi;
    int j64 = bi + (g0 - bi * (257 - bi) / 2);

    __shared__ uint4 Bs[4][3][128];      // [wave][buf][16 cols x 8 pieces] 2KB/buf
    char* lpanel = (char*)&Bs[wave][0][0];
    const int laneoff = (lane >> 3) * 128 + (((lane & 7) ^ ((lane >> 3) & 7)) << 4);
    const int slot0 = rp * 8;
    const int sw = rp & 7;

    // initial A fragments for stripe bi: row = bi*64 + rt*16 + rp, k [q*32,+32)
    i32x8 afr[4];
    {
        const unsigned char* Ab = Rb + (size_t)(bi * 64 + rp) * 128 + q * 32;
        #pragma unroll
        for (int rt = 0; rt < 4; ++rt) {
            uint4 h0 = *(const uint4*)(Ab + rt * 16 * 128);
            uint4 h1 = *(const uint4*)(Ab + rt * 16 * 128 + 16);
            afr[rt] = mk8(h0, h1);
        }
    }
    float rs[16];
    #pragma unroll
    for (int i = 0; i < 16; ++i) rs[i] = 0.f;
    int aBi = bi;                        // stripe currently held in afr/rs

    // prologue: prefetch tiles g0 (buf0), g0+1 (buf1)
    int wBi = bi, wJ = j64;              // prefetch walker
    #pragma unroll
    for (int j = 0; j < 2; ++j) {
        if (j < nt) {
            const unsigned char* gp = Rb + (size_t)(wJ * 64 + wave * 16) * 128 + laneoff;
            async_ld16(lpanel + j * 2048, gp);
            async_ld16(lpanel + j * 2048 + 1024, gp + 1024);
            if (++wJ == 128) { ++wBi; wJ = wBi; }
        }
    }

    int cBi = bi, cJ = j64;              // current-tile walker
    int cur = 0;                         // current LDS buffer

    for (int i = 0; i < nt; ++i) {
        if (cBi != aBi) {                // stripe change: flush + reload A
            #pragma unroll
            for (int t2 = 0; t2 < 16; ++t2) {
                float v = rs[t2];
                v += __shfl_xor(v, 1, 64);
                v += __shfl_xor(v, 2, 64);
                v += __shfl_xor(v, 4, 64);
                v += __shfl_xor(v, 8, 64);
                if (rp == 0)
                    atomicAdd(rowsum + aBi * 64 + (t2 >> 2) * 16 + q * 4 + (t2 & 3), v);
                rs[t2] = 0.f;
            }
            const unsigned char* Ab = Rb + (size_t)(cBi * 64 + rp) * 128 + q * 32;
            #pragma unroll
            for (int rt = 0; rt < 4; ++rt) {
                uint4 h0 = *(const uint4*)(Ab + rt * 16 * 128);
                uint4 h1 = *(const uint4*)(Ab + rt * 16 * 128 + 16);
                afr[rt] = mk8(h0, h1);
            }
            aBi = cBi;
        }

        // wait for the OLDEST panel only; next tile's DMAs stay in flight
        if (i < nt - 2) __builtin_amdgcn_s_waitcnt(0x0F72);   // vmcnt(2)
        else            __builtin_amdgcn_s_waitcnt(0x0F70);   // vmcnt(0)

        const uint4* P = &Bs[wave][0][0] + cur * 128;
        uint4 u0 = P[slot0 + ((q * 2 + 0) ^ sw)];
        uint4 u1 = P[slot0 + ((q * 2 + 1) ^ sw)];
        i32x8 bfr = mk8(u0, u1);

        if (i + 2 < nt) {                // prefetch tile i+2 into buf (cur+2)%3
            const int nb = (cur >= 1) ? cur - 1 : 2;
            const unsigned char* gp = Rb + (size_t)(wJ * 64 + wave * 16) * 128 + laneoff;
            async_ld16(lpanel + nb * 2048, gp);
            async_ld16(lpanel + nb * 2048 + 1024, gp + 1024);
            if (++wJ == 128) { ++wBi; wJ = wBi; }
        }

        f32x4 acc[4];
        #pragma unroll
        for (int rt = 0; rt < 4; ++rt) {
            f32x4 z = {0.f, 0.f, 0.f, 0.f};
            acc[rt] = __builtin_amdgcn_mfma_scale_f32_16x16x128_f8f6f4(
                afr[rt], bfr, z,
                0, 0,                     // cbsz=fp8(e4m3), blgp=fp8(e4m3)
                0, 0x7F7F7F7F,            // A scale opsel, scale = 1.0
                0, 0x7F7F7F7F);           // B scale opsel, scale = 1.0
        }

        // D layout: col(tile-local) = wave*16 + rp, row = rt*16 + q*4 + r
        if (cJ == cBi) {                 // diagonal tile: zero ro==co, no col emit
            #pragma unroll
            for (int rt = 0; rt < 4; ++rt)
                #pragma unroll
                for (int r = 0; r < 4; ++r) {
                    int ro = rt * 16 + q * 4 + r;
                    int co = wave * 16 + rp;
                    float e = __builtin_amdgcn_exp2f(acc[rt][r]);
                    rs[rt * 4 + r] += (ro == co) ? 0.f : e;
                }
        } else {                         // strictly-above: row-sum + col emission
            float csum = 0.f;
            #pragma unroll
            for (int rt = 0; rt < 4; ++rt)
                #pragma unroll
                for (int r = 0; r < 4; ++r) {
                    float e = __builtin_amdgcn_exp2f(acc[rt][r]);
                    rs[rt * 4 + r] += e;
                    csum += e;
                }
            csum += __shfl_xor(csum, 16, 64);
            csum += __shfl_xor(csum, 32, 64);
            if (q == 0)
                atomicAdd(colpart + cJ * 64 + wave * 16 + rp, csum);
        }

        cur = (cur == 2) ? 0 : cur + 1;
        if (++cJ == 128) { ++cBi; cJ = cBi; }
    }

    // final flush for the last stripe
    #pragma unroll
    for (int t2 = 0; t2 < 16; ++t2) {
        float v = rs[t2];
        v += __shfl_xor(v, 1, 64);
        v += __shfl_xor(v, 2, 64);
        v += __shfl_xor(v, 4, 64);
        v += __shfl_xor(v, 8, 64);
        if (rp == 0)
            atomicAdd(rowsum + aBi * 64 + (t2 >> 2) * 16 + q * 4 + (t2 & 3), v);
    }
}

// 64 blocks x 128 threads; each thread owns one row: rowsum + colpart, then
// log/exp epilogue; one atomicAdd per block.
__global__ __launch_bounds__(128) void finalize_kernel(const float* __restrict__ rowsum,
                                                       const float* __restrict__ colpart,
                                                       const float* __restrict__ pos,
                                                       float* __restrict__ out) {
    __shared__ float red[2];
    int tid = threadIdx.x;
    int k = blockIdx.x * 128 + tid;
    float rsum = rowsum[k] + colpart[k];
    float ps = pos[k & (NPAIR - 1)];
    float p2 = ps + ps;
    float local = logf(rsum + __expf(p2)) - p2;
    #pragma unroll
    for (int m = 1; m < 64; m <<= 1) local += __shfl_xor(local, m, 64);
    if ((tid & 63) == 0) red[tid >> 6] = local;
    __syncthreads();
    if (tid == 0) atomicAdd(out, (red[0] + red[1]) * (1.0f / (float)TWO_N));
}

extern "C" void kernel_launch(void* const* d_in, const int* in_sizes, int n_in,
                              void* d_out, int out_size, void* d_ws, size_t ws_size,
                              hipStream_t stream) {
    const float* zi = (const float*)d_in[0];
    const float* zj = (const float*)d_in[1];
    char* ws = (char*)d_ws;
    unsigned char* Rb = (unsigned char*)ws;                         // 1 MB fp8 rows
    float* rowsum = (float*)(ws + 1 * 1024 * 1024);                 // 32 KB
    float* colpart = (float*)(ws + 1 * 1024 * 1024 + 32 * 1024);    // 32 KB
    float* pos = (float*)(ws + 1 * 1024 * 1024 + 64 * 1024);        // 16 KB

    norm_kernel<<<NPAIR / 8, 256, 0, stream>>>(zi, zj, Rb, pos, rowsum, colpart, (float*)d_out);
    simexp_kernel<<<1024, 256, 0, stream>>>(Rb, rowsum, colpart);
    finalize_kernel<<<64, 128, 0, stream>>>(rowsum, colpart, pos, (float*)d_out);
}

// Round 7
// 78.297 us; speedup vs baseline: 1.1111x; 1.1111x over previous
//
#include <hip/hip_runtime.h>
#include <hip/hip_bf16.h>
#include <math.h>

#define NPAIR 4096       // N = B*S
#define D 128
#define TWO_N 8192
#define NSLAB 32         // 8 jc-slabs x 4 waves, race-free partial rows
// Rb rows pre-scaled by ALPHA = sqrt(2*log2(e)): MFMA acc == 2*log2(e)*sim,
// so exp(2*sim) == exp2(acc) -> a single raw v_exp_f32 in the epilogue.
#define ALPHA 1.6986436f

typedef float f32x4 __attribute__((ext_vector_type(4)));
typedef int i32x8 __attribute__((ext_vector_type(8)));

__device__ __forceinline__ void async_ld16(void* lds, const void* g) {
    // async global->LDS DMA, 16B/lane; LDS dest = wave-uniform base + lane*16
    __builtin_amdgcn_global_load_lds(
        (__attribute__((address_space(1))) const unsigned int*)g,
        (__attribute__((address_space(3))) unsigned int*)lds, 16, 0, 0);
}

__device__ __forceinline__ i32x8 mk8(uint4 lo, uint4 hi) {
    return (i32x8){(int)lo.x, (int)lo.y, (int)lo.z, (int)lo.w,
                   (int)hi.x, (int)hi.y, (int)hi.z, (int)hi.w};
}

// 512 blocks x 256 threads; half-wave h (32 lanes) handles pair-row
// k = blockIdx*8 + h, 4 elems/lane via float4. Emits ALPHA-scaled fp8 e4m3
// rows, PLAIN ROW-MAJOR, one dword store per lane per row.
// pos[] stays exact fp32. Zero-inits out[0].  [PASSED r1/r3/r4/r5/r6]
__global__ __launch_bounds__(256) void norm_kernel(const float* __restrict__ zi,
                                                   const float* __restrict__ zj,
                                                   unsigned char* __restrict__ Rb,
                                                   float* __restrict__ pos,
                                                   float* __restrict__ out) {
    if (blockIdx.x == 0 && threadIdx.x == 0) out[0] = 0.f;
    int k = blockIdx.x * 8 + (threadIdx.x >> 5);
    int t = threadIdx.x & 31;                 // 4 elems each
    const float4 a = *(const float4*)(zi + k * D + 4 * t);
    const float4 b = *(const float4*)(zj + k * D + 4 * t);
    float si = a.x * a.x + a.y * a.y + a.z * a.z + a.w * a.w;
    float sj = b.x * b.x + b.y * b.y + b.z * b.z + b.w * b.w;
    float dt = a.x * b.x + a.y * b.y + a.z * b.z + a.w * b.w;
    #pragma unroll
    for (int m = 1; m < 32; m <<= 1) {        // reduce within the 32-lane row
        si += __shfl_xor(si, m, 32);
        sj += __shfl_xor(sj, m, 32);
        dt += __shfl_xor(dt, m, 32);
    }
    float ii = 1.0f / fmaxf(sqrtf(si), 1e-12f);
    float ij = 1.0f / fmaxf(sqrtf(sj), 1e-12f);
    if (t == 0) pos[k] = dt * ii * ij;        // exact (unscaled) positive sim
    ii *= ALPHA; ij *= ALPHA;
    int r0 = __builtin_amdgcn_cvt_pk_fp8_f32(a.x * ii, a.y * ii, 0, false);
    r0 = __builtin_amdgcn_cvt_pk_fp8_f32(a.z * ii, a.w * ii, r0, true);
    *(unsigned int*)(Rb + (size_t)k * 128 + 4 * t) = (unsigned int)r0;
    int r1 = __builtin_amdgcn_cvt_pk_fp8_f32(b.x * ij, b.y * ij, 0, false);
    r1 = __builtin_amdgcn_cvt_pk_fp8_f32(b.z * ij, b.w * ij, r1, true);
    *(unsigned int*)(Rb + (size_t)(k + NPAIR) * 128 + 4 * t) = (unsigned int)r1;
}

// ROUND-0 PROVEN STRUCTURE, restored verbatim: full matrix, LDS triple-buffer
// DMA, vmcnt(2), XOR slots, static 16-jt unroll, zero barriers. r3-r6 lesson:
// every deviation (reg-B, slab masking, tile walker) cost 5-10us — the
// compiler's static schedule of THIS loop is the asset. Only two
// schedule-preserving micro-reductions on top:
//  (1) persistent z0 as the MFMA C-operand (D != C): deletes 16 acc
//      zero-writes per jt per wave (r5's marginal-VALU evidence: ~1:1 wall).
//  (2) s_setprio(1) around the MFMA cluster: barrier-free independent waves
//      == the attn-like regime where T5 measured +4-7% (m191).
__global__ __launch_bounds__(256, 4) void simexp_kernel(const unsigned char* __restrict__ Rb,
                                                        float* __restrict__ rspart) {
    __shared__ uint4 Bs[4][3][128];      // [wave][buf][16 cols x 8 pieces] 2KB/buf
    const int bi = blockIdx.x >> 3;      // 0..127 (64-row stripe)
    const int jc = blockIdx.x & 7;       // 0..7  (1024-col slab)
    const int tid = threadIdx.x;
    const int wave = tid >> 6, lane = tid & 63;
    const int rp = lane & 15, q = lane >> 4;

    // A fragments: row = bi*64 + rt*16 + rp; lane's k [q*32, q*32+32).
    i32x8 afr[4];                        // [rt]
    {
        const unsigned char* Ab = Rb + (size_t)(bi * 64 + rp) * 128 + q * 32;
        #pragma unroll
        for (int rt = 0; rt < 4; ++rt) {
            uint4 h0 = *(const uint4*)(Ab + rt * 16 * 128);
            uint4 h1 = *(const uint4*)(Ab + rt * 16 * 128 + 16);
            afr[rt] = mk8(h0, h1);
        }
    }

    // Wave-private B panel: cols jc*1024 + jt*64 + wave*16 + [0,16), 128B/col,
    // 2 DMAs/jt (8 cols each). DMA d, lane l: col cr = d*8 + (l>>3), stored
    // piece p' = l&7, global piece p = p' ^ (cr&7)  [slot = cr*8 + (p^(cr&7))].
    const unsigned char* gslab = Rb + (size_t)(jc * 1024 + wave * 16) * 128;
    char* lpanel = (char*)&Bs[wave][0][0];
    const int laneoff = (lane >> 3) * 128 + (((lane & 7) ^ ((lane >> 3) & 7)) << 4);

    float rs[16];
    #pragma unroll
    for (int i = 0; i < 16; ++i) rs[i] = 0.f;

    // prefetch jt=0 (buf0) and jt=1 (buf1): 4 DMAs outstanding
    #pragma unroll
    for (int j = 0; j < 2; ++j)
        #pragma unroll
        for (int d = 0; d < 2; ++d)
            async_ld16(lpanel + j * 2048 + d * 1024,
                       gslab + j * 8192 + d * 1024 + laneoff);

    const int diagbase = bi * 64 - jc * 1024;   // diag col offset in slab
    const int slot0 = rp * 8;
    const int sw = rp & 7;

    // persistent zero C-operand: zeroed ONCE; MFMA writes D=acc (D != C),
    // so no per-jt accumulator zeroing instructions.
    f32x4 z0 = {0.f, 0.f, 0.f, 0.f};

    #pragma unroll
    for (int jt = 0; jt < 16; ++jt) {
        // Wait only for the OLDEST panel (this jt's 2 DMAs); next stays in flight.
        if (jt < 14) __builtin_amdgcn_s_waitcnt(0x0F72);   // vmcnt(2)
        else         __builtin_amdgcn_s_waitcnt(0x0F70);   // vmcnt(0)

        const int cur = jt % 3;
        const uint4* P = &Bs[wave][cur][0];
        // lane needs col rp pieces 2q (k low half) and 2q+1 (k high half)
        uint4 u0 = P[slot0 + ((q * 2 + 0) ^ sw)];
        uint4 u1 = P[slot0 + ((q * 2 + 1) ^ sw)];
        i32x8 bfr = mk8(u0, u1);

        if (jt < 14) {                   // prefetch jt+2 into buf (jt+2)%3
            const int nb = (jt + 2) % 3;
            #pragma unroll
            for (int d = 0; d < 2; ++d)
                async_ld16(lpanel + nb * 2048 + d * 1024,
                           gslab + (jt + 2) * 8192 + d * 1024 + laneoff);
        }

        f32x4 acc[4];
        __builtin_amdgcn_s_setprio(1);
        #pragma unroll
        for (int rt = 0; rt < 4; ++rt)
            acc[rt] = __builtin_amdgcn_mfma_scale_f32_16x16x128_f8f6f4(
                afr[rt], bfr, z0,
                0, 0,                     // cbsz=fp8(e4m3), blgp=fp8(e4m3)
                0, 0x7F7F7F7F,            // A scale opsel, scale = 1.0
                0, 0x7F7F7F7F);           // B scale opsel, scale = 1.0
        __builtin_amdgcn_s_setprio(0);

        // D layout: col(tile-local) = wave*16 + rp, row = rt*16 + q*4 + r
        if (jt * 64 == diagbase) {       // the one jt tile holding the diagonal
            #pragma unroll
            for (int rt = 0; rt < 4; ++rt)
                #pragma unroll
                for (int r = 0; r < 4; ++r) {
                    int ro = rt * 16 + q * 4 + r;
                    int co = wave * 16 + rp;
                    float e = __builtin_amdgcn_exp2f(acc[rt][r]);
                    rs[rt * 4 + r] += (ro == co) ? 0.f : e;
                }
        } else {
            #pragma unroll
            for (int rt = 0; rt < 4; ++rt)
                #pragma unroll
                for (int r = 0; r < 4; ++r)
                    rs[rt * 4 + r] += __builtin_amdgcn_exp2f(acc[rt][r]);
        }
    }

    // Reduce each reg across the 16 rp lanes; rp==0 stores its 16 rows.
    #pragma unroll
    for (int i = 0; i < 16; ++i) {
        float v = rs[i];
        v += __shfl_xor(v, 1, 64);
        v += __shfl_xor(v, 2, 64);
        v += __shfl_xor(v, 4, 64);
        v += __shfl_xor(v, 8, 64);
        rs[i] = v;
    }
    if (rp == 0) {
        const int slab = jc * 4 + wave;
        const int rowb = bi * 64 + q * 4;
        // rspart layout [row][slab] so finalize reads are float4-vectorizable
        // [this tail PASSED in r5's diag-path blocks]
        #pragma unroll
        for (int rt = 0; rt < 4; ++rt)
            #pragma unroll
            for (int r = 0; r < 4; ++r)
                rspart[(size_t)(rowb + rt * 16 + r) * NSLAB + slab] = rs[rt * 4 + r];
    }
}

// 64 blocks x 128 threads; each thread owns one row: 8x float4 loads of its
// 32 slab partials, then log/exp epilogue; one atomicAdd per block.
// [PASSED r1/r3/r4]
__global__ __launch_bounds__(128) void finalize_kernel(const float* __restrict__ rspart,
                                                       const float* __restrict__ pos,
                                                       float* __restrict__ out) {
    __shared__ float red[2];
    int tid = threadIdx.x;
    int k = blockIdx.x * 128 + tid;
    const f32x4* v = (const f32x4*)(rspart + (size_t)k * NSLAB);
    f32x4 s = v[0];
    #pragma unroll
    for (int p = 1; p < 8; ++p) s += v[p];
    float rsum = s.x + s.y + s.z + s.w;
    float ps = pos[k & (NPAIR - 1)];
    float p2 = ps + ps;
    float local = logf(rsum + __expf(p2)) - p2;
    #pragma unroll
    for (int m = 1; m < 64; m <<= 1) local += __shfl_xor(local, m, 64);
    if ((tid & 63) == 0) red[tid >> 6] = local;
    __syncthreads();
    if (tid == 0) atomicAdd(out, (red[0] + red[1]) * (1.0f / (float)TWO_N));
}

extern "C" void kernel_launch(void* const* d_in, const int* in_sizes, int n_in,
                              void* d_out, int out_size, void* d_ws, size_t ws_size,
                              hipStream_t stream) {
    const float* zi = (const float*)d_in[0];
    const float* zj = (const float*)d_in[1];
    char* ws = (char*)d_ws;
    unsigned char* Rb = (unsigned char*)ws;                         // 1 MB fp8 rows
    float* rspart = (float*)(ws + 1 * 1024 * 1024);                 // 8192*32*4 = 1 MB
    float* pos = (float*)(ws + 2 * 1024 * 1024);                    // 16 KB

    norm_kernel<<<NPAIR / 8, 256, 0, stream>>>(zi, zj, Rb, pos, (float*)d_out);
    simexp_kernel<<<128 * 8, 256, 0, stream>>>(Rb, rspart);
    finalize_kernel<<<64, 128, 0, stream>>>(rspart, pos, (float*)d_out);
}